// Round 1
// baseline (1659.859 us; speedup 1.0000x reference)
//
#include <hip/hip_runtime.h>

// Problem constants (match reference)
#define N_PTS 1048576
#define C_PT 9
#define C_LB 20
#define V1 500000
#define V8 65536

// One thread per point: scatter-add its 9 point features into feat_sum[v1],
// its 20 label floats into lbl_sum[v8], and bump both counts.
__global__ void voxel_scatter_add_kernel(const float* __restrict__ points,
                                         const int* __restrict__ inv1,
                                         const float* __restrict__ labels,
                                         const int* __restrict__ inv8,
                                         float* __restrict__ feat_sum,   // [V1, C_PT] (lives in d_out)
                                         float* __restrict__ lbl_sum,    // [V8, C_LB] (lives in d_out)
                                         float* __restrict__ cnt1,       // [V1] (d_ws)
                                         float* __restrict__ cnt8)       // [V8] (d_ws)
{
    int i = blockIdx.x * blockDim.x + threadIdx.x;
    if (i >= N_PTS) return;

    int v1 = inv1[i];
    int v8 = inv8[i];

    const float* __restrict__ p = points + (size_t)i * C_PT;
    float* __restrict__ f = feat_sum + (size_t)v1 * C_PT;
#pragma unroll
    for (int c = 0; c < C_PT; ++c)
        atomicAdd(&f[c], p[c]);
    atomicAdd(&cnt1[v1], 1.0f);

    const float* __restrict__ l = labels + (size_t)i * C_LB;
    float* __restrict__ o = lbl_sum + (size_t)v8 * C_LB;
#pragma unroll
    for (int c = 0; c < C_LB; ++c)
        atomicAdd(&o[c], l[c]);
    atomicAdd(&cnt8[v8], 1.0f);
}

// Divide sums by max(count, 1) over the whole flat output.
__global__ void voxel_divide_kernel(float* __restrict__ out,
                                    const float* __restrict__ cnt1,
                                    const float* __restrict__ cnt8)
{
    const int total = V1 * C_PT + V8 * C_LB;
    for (int i = blockIdx.x * blockDim.x + threadIdx.x; i < total;
         i += gridDim.x * blockDim.x) {
        float c;
        if (i < V1 * C_PT) {
            c = cnt1[i / C_PT];
        } else {
            c = cnt8[(i - V1 * C_PT) / C_LB];
        }
        out[i] /= fmaxf(c, 1.0f);
    }
}

extern "C" void kernel_launch(void* const* d_in, const int* in_sizes, int n_in,
                              void* d_out, int out_size, void* d_ws, size_t ws_size,
                              hipStream_t stream) {
    const float* points = (const float*)d_in[0];
    const int*   inv1   = (const int*)d_in[1];
    const float* labels = (const float*)d_in[2];
    const int*   inv8   = (const int*)d_in[3];

    float* out      = (float*)d_out;
    float* feat_sum = out;                        // [V1, C_PT]
    float* lbl_sum  = out + (size_t)V1 * C_PT;    // [V8, C_LB]

    float* cnt1 = (float*)d_ws;                   // [V1]
    float* cnt8 = cnt1 + V1;                      // [V8]

    // Zero the accumulators every call (harness poisons with 0xAA and does
    // not re-poison between graph replays).
    hipMemsetAsync(d_out, 0, (size_t)out_size * sizeof(float), stream);
    hipMemsetAsync(d_ws, 0, (size_t)(V1 + V8) * sizeof(float), stream);

    const int block = 256;
    const int grid_scatter = (N_PTS + block - 1) / block;
    voxel_scatter_add_kernel<<<grid_scatter, block, 0, stream>>>(
        points, inv1, labels, inv8, feat_sum, lbl_sum, cnt1, cnt8);

    voxel_divide_kernel<<<2048, block, 0, stream>>>(out, cnt1, cnt8);
}

// Round 2
// 185.923 us; speedup vs baseline: 8.9277x; 8.9277x over previous
//
#include <hip/hip_runtime.h>

// Problem constants (match reference)
#define N_PTS 1048576
#define C_PT 9
#define C_LB 20
#define V1 500000
#define V8 65536

// ---------------- Linked-list gather path ----------------
// Phase B: 1 atomicExch per point per scale builds a per-voxel singly-linked
// list (head[v] -> chain of point indices via next[]). 2M atomics total vs
// 31.5M atomicAdds in the naive scatter (fabric atomic rate ~19 G/s was the
// R0 bottleneck: WRITE_SIZE == 32B * n_atomics exactly).
__global__ void build_lists_kernel(const int* __restrict__ inv1,
                                   const int* __restrict__ inv8,
                                   int* __restrict__ head1,
                                   int* __restrict__ next1,
                                   int* __restrict__ head8,
                                   int* __restrict__ next8)
{
    int i = blockIdx.x * blockDim.x + threadIdx.x;
    if (i >= N_PTS) return;
    int v1 = inv1[i];
    int v8 = inv8[i];
    next1[i] = atomicExch(&head1[v1], i);
    next8[i] = atomicExch(&head8[v8], i);
}

// Phase C: one thread per output voxel walks its list, accumulates in
// registers, writes each output element exactly once (coalesced-ish, no
// atomics). Label blocks first (longer chains, ~16 nodes) so they start early.
__global__ void walk_kernel(const float* __restrict__ points,
                            const float* __restrict__ labels,
                            const int* __restrict__ head1,
                            const int* __restrict__ next1,
                            const int* __restrict__ head8,
                            const int* __restrict__ next8,
                            float* __restrict__ feat_out,  // [V1, C_PT]
                            float* __restrict__ lbl_out)   // [V8, C_LB]
{
    const int LBL_BLOCKS = (V8 + 255) / 256;   // 256 blocks
    int bid = blockIdx.x;
    if (bid < LBL_BLOCKS) {
        int v = bid * 256 + threadIdx.x;
        if (v >= V8) return;
        float s[C_LB];
#pragma unroll
        for (int c = 0; c < C_LB; ++c) s[c] = 0.0f;
        int cnt = 0;
        int ptr = head8[v];
        while (ptr >= 0) {
            const float* __restrict__ l = labels + (size_t)ptr * C_LB;
#pragma unroll
            for (int c = 0; c < C_LB; ++c) s[c] += l[c];
            ++cnt;
            ptr = next8[ptr];
        }
        float inv = 1.0f / (float)(cnt > 0 ? cnt : 1);
        float* __restrict__ o = lbl_out + (size_t)v * C_LB;
#pragma unroll
        for (int c = 0; c < C_LB; ++c) o[c] = s[c] * inv;
    } else {
        int v = (bid - LBL_BLOCKS) * 256 + threadIdx.x;
        if (v >= V1) return;
        float s[C_PT];
#pragma unroll
        for (int c = 0; c < C_PT; ++c) s[c] = 0.0f;
        int cnt = 0;
        int ptr = head1[v];
        while (ptr >= 0) {
            const float* __restrict__ p = points + (size_t)ptr * C_PT;
#pragma unroll
            for (int c = 0; c < C_PT; ++c) s[c] += p[c];
            ++cnt;
            ptr = next1[ptr];
        }
        float inv = 1.0f / (float)(cnt > 0 ? cnt : 1);
        float* __restrict__ o = feat_out + (size_t)v * C_PT;
#pragma unroll
        for (int c = 0; c < C_PT; ++c) o[c] = s[c] * inv;
    }
}

// ---------------- Fallback (R0 atomic scatter) — only if ws too small ------
__global__ void voxel_scatter_add_kernel(const float* __restrict__ points,
                                         const int* __restrict__ inv1,
                                         const float* __restrict__ labels,
                                         const int* __restrict__ inv8,
                                         float* __restrict__ feat_sum,
                                         float* __restrict__ lbl_sum,
                                         float* __restrict__ cnt1,
                                         float* __restrict__ cnt8)
{
    int i = blockIdx.x * blockDim.x + threadIdx.x;
    if (i >= N_PTS) return;
    int v1 = inv1[i];
    int v8 = inv8[i];
    const float* p = points + (size_t)i * C_PT;
    float* f = feat_sum + (size_t)v1 * C_PT;
#pragma unroll
    for (int c = 0; c < C_PT; ++c) atomicAdd(&f[c], p[c]);
    atomicAdd(&cnt1[v1], 1.0f);
    const float* l = labels + (size_t)i * C_LB;
    float* o = lbl_sum + (size_t)v8 * C_LB;
#pragma unroll
    for (int c = 0; c < C_LB; ++c) atomicAdd(&o[c], l[c]);
    atomicAdd(&cnt8[v8], 1.0f);
}

__global__ void voxel_divide_kernel(float* __restrict__ out,
                                    const float* __restrict__ cnt1,
                                    const float* __restrict__ cnt8)
{
    const int total = V1 * C_PT + V8 * C_LB;
    for (int i = blockIdx.x * blockDim.x + threadIdx.x; i < total;
         i += gridDim.x * blockDim.x) {
        float c = (i < V1 * C_PT) ? cnt1[i / C_PT] : cnt8[(i - V1 * C_PT) / C_LB];
        out[i] /= fmaxf(c, 1.0f);
    }
}

extern "C" void kernel_launch(void* const* d_in, const int* in_sizes, int n_in,
                              void* d_out, int out_size, void* d_ws, size_t ws_size,
                              hipStream_t stream) {
    const float* points = (const float*)d_in[0];
    const int*   inv1   = (const int*)d_in[1];
    const float* labels = (const float*)d_in[2];
    const int*   inv8   = (const int*)d_in[3];

    float* out      = (float*)d_out;
    float* feat_out = out;                       // [V1, C_PT]
    float* lbl_out  = out + (size_t)V1 * C_PT;   // [V8, C_LB]

    const size_t need = ((size_t)V1 + (size_t)V8 + 2 * (size_t)N_PTS) * sizeof(int);
    if (ws_size >= need) {
        int* head1 = (int*)d_ws;            // [V1]
        int* head8 = head1 + V1;            // [V8]
        int* next1 = head8 + V8;            // [N]
        int* next8 = next1 + N_PTS;         // [N]

        // heads = -1 (0xFF bytes). next[] fully written by build kernel.
        hipMemsetAsync(head1, 0xFF, ((size_t)V1 + V8) * sizeof(int), stream);

        const int block = 256;
        build_lists_kernel<<<(N_PTS + block - 1) / block, block, 0, stream>>>(
            inv1, inv8, head1, next1, head8, next8);

        const int lbl_blocks  = (V8 + block - 1) / block;   // 256
        const int feat_blocks = (V1 + block - 1) / block;   // 1954
        walk_kernel<<<lbl_blocks + feat_blocks, block, 0, stream>>>(
            points, labels, head1, next1, head8, next8, feat_out, lbl_out);
    } else {
        // Fallback: naive atomic scatter (correct, slower).
        float* cnt1 = (float*)d_ws;
        float* cnt8 = cnt1 + V1;
        hipMemsetAsync(d_out, 0, (size_t)out_size * sizeof(float), stream);
        hipMemsetAsync(d_ws, 0, ((size_t)V1 + V8) * sizeof(float), stream);
        const int block = 256;
        voxel_scatter_add_kernel<<<(N_PTS + block - 1) / block, block, 0, stream>>>(
            points, inv1, labels, inv8, feat_out, lbl_out, cnt1, cnt8);
        voxel_divide_kernel<<<2048, block, 0, stream>>>(out, cnt1, cnt8);
    }
}